// Round 2
// baseline (1142.469 us; speedup 1.0000x reference)
//
#include <hip/hip_runtime.h>

#define DF 64

// ---- degree accumulation: deg[dst] += w  (self-loop +1 folded into dinv) ----
__global__ void deg_kernel(const int* __restrict__ ei, const float* __restrict__ w,
                           float* __restrict__ deg, int E) {
  int i = blockIdx.x * blockDim.x + threadIdx.x;
  if (i < E) {
    int dst = ei[E + i];
    unsafeAtomicAdd(&deg[dst], w[i]);
  }
}

__global__ void dinv_kernel(float* __restrict__ deg, int n) {
  int i = blockIdx.x * blockDim.x + threadIdx.x;
  if (i < n) deg[i] = rsqrtf(deg[i] + 1.0f);
}

// ---- GEMM [n,64] x [64,64] fp32 VALU: wave per row, W in LDS ----
__global__ __launch_bounds__(256) void gemm_valu(const float* __restrict__ A,
                                                 const float* __restrict__ W,
                                                 float* __restrict__ out, int n) {
  __shared__ float Wl[DF * DF];
  for (int t = threadIdx.x; t < DF * DF; t += 256) Wl[t] = W[t];
  __syncthreads();
  int f = threadIdx.x & 63;
  int sub = threadIdx.x >> 6;
  for (int i = blockIdx.x * 4 + sub; i < n; i += gridDim.x * 4) {
    float xv = A[(size_t)i * DF + f];
    float acc = 0.f;
#pragma unroll
    for (int k = 0; k < DF; k++) {
      float xs = __shfl(xv, k, 64);              // row broadcast
      acc += xs * Wl[k * DF + f];                // 2 lanes/bank: conflict-free
    }
    out[(size_t)i * DF + f] = acc;
  }
}

// ---- acc[i,:] = xl[i,:]*dinv[i]^2 + b  (self-loop term == accumulator init) ----
__global__ void init_acc(const float* __restrict__ xl, const float* __restrict__ dinv,
                         const float* __restrict__ b, float* __restrict__ acc, int n) {
  int i = blockIdx.x * 4 + (threadIdx.x >> 6);
  if (i >= n) return;
  int f = threadIdx.x & 63;
  float di = dinv[i];
  acc[(size_t)i * DF + f] = xl[(size_t)i * DF + f] * di * di + b[f];
}

// ---- edge scatter: wave per edge, lane = feature ----
__global__ void scatter_kernel(const int* __restrict__ ei, const float* __restrict__ w,
                               const float* __restrict__ dinv, const float* __restrict__ xl,
                               float* __restrict__ acc, int E) {
  int e = blockIdx.x * 4 + (threadIdx.x >> 6);
  if (e >= E) return;
  int f = threadIdx.x & 63;
  int src = ei[e], dst = ei[E + e];
  float nrm = dinv[src] * w[e] * dinv[dst];
  unsafeAtomicAdd(&acc[(size_t)dst * DF + f], xl[(size_t)src * DF + f] * nrm);
}

// ---- BN stats: per-feature sum / sumsq ----
__global__ void stats_kernel(const float* __restrict__ acc, float* __restrict__ stats, int n) {
  int f = threadIdx.x & 63;
  int sub = threadIdx.x >> 6;
  float s = 0.f, ss = 0.f;
  for (int i = blockIdx.x * 4 + sub; i < n; i += gridDim.x * 4) {
    float v = acc[(size_t)i * DF + f];
    s += v;
    ss += v * v;
  }
  __shared__ float ls[4][DF], lss[4][DF];
  ls[sub][f] = s;
  lss[sub][f] = ss;
  __syncthreads();
  if (threadIdx.x < DF) {
    float t1 = ls[0][f] + ls[1][f] + ls[2][f] + ls[3][f];
    float t2 = lss[0][f] + lss[1][f] + lss[2][f] + lss[3][f];
    unsafeAtomicAdd(&stats[f], t1);
    unsafeAtomicAdd(&stats[DF + f], t2);
  }
}

// ---- fold mean/var/gamma/beta into y = h*s + t ----
__global__ void finalize_stats(float* __restrict__ stats, const float* __restrict__ gamma,
                               const float* __restrict__ beta, int n) {
  int f = threadIdx.x;
  if (f >= DF) return;
  float mean = stats[f] / n;
  float var = stats[DF + f] / n - mean * mean;
  float rstd = rsqrtf(var + 1e-5f);
  float s = gamma[f] * rstd;
  stats[128 + f] = s;
  stats[192 + f] = beta[f] - mean * s;
}

// ---- BN apply + PReLU -> fp32 (in-place safe: same thread reads/writes elem) ----
__global__ void bnapply(const float* __restrict__ acc, const float* __restrict__ stats,
                        const float* __restrict__ alpha_p, float* __restrict__ outb, int n) {
  int i = blockIdx.x * 4 + (threadIdx.x >> 6);
  if (i >= n) return;
  int f = threadIdx.x & 63;
  float y = acc[(size_t)i * DF + f] * stats[128 + f] + stats[192 + f];
  float a = alpha_p[0];
  y = (y >= 0.f) ? y : a * y;
  outb[(size_t)i * DF + f] = y;
}

extern "C" void kernel_launch(void* const* d_in, const int* in_sizes, int n_in,
                              void* d_out, int out_size, void* d_ws, size_t ws_size,
                              hipStream_t stream) {
  const float* x  = (const float*)d_in[0];
  const int* ei   = (const int*)d_in[1];
  const float* w  = (const float*)d_in[2];
  const float* W1 = (const float*)d_in[3];
  const float* b1 = (const float*)d_in[4];
  const float* g1 = (const float*)d_in[5];
  const float* be1= (const float*)d_in[6];
  const float* al1= (const float*)d_in[7];
  const float* W2 = (const float*)d_in[8];
  const float* b2 = (const float*)d_in[9];
  const float* g2 = (const float*)d_in[10];
  const float* be2= (const float*)d_in[11];
  const float* al2= (const float*)d_in[12];
  float* out = (float*)d_out;

  const int n = in_sizes[0] / DF;
  const int E = in_sizes[2];

  float* ws = (float*)d_ws;
  const size_t stats_off = ((size_t)n + 63) & ~(size_t)63;
  const size_t R1_off = stats_off + 256;
  const size_t R2_off = R1_off + (size_t)n * DF;
  float* deg = ws;
  float* stats = ws + stats_off;
  float* R1 = ws + R1_off;
  float* R2 = ws + R2_off;

  const int nb_nodes = (n + 3) / 4;   // 4 rows / 256-thr block
  const int nb_edges = (E + 3) / 4;   // 4 edges / 256-thr block
  const int nb_gemm = 2048;           // grid-stride
  const int nb_stats = 1024;

  // zero deg + stats (ws is poisoned 0xAA before every call)
  hipMemsetAsync(deg, 0, (stats_off + 256) * sizeof(float), stream);

  deg_kernel<<<(E + 255) / 256, 256, 0, stream>>>(ei, w, deg, E);
  dinv_kernel<<<(n + 255) / 256, 256, 0, stream>>>(deg, n);

  // ---- layer 1 ----
  gemm_valu<<<nb_gemm, 256, 0, stream>>>(x, W1, R1, n);          // xl1 -> R1
  init_acc<<<nb_nodes, 256, 0, stream>>>(R1, deg, b1, R2, n);    // acc1 -> R2
  scatter_kernel<<<nb_edges, 256, 0, stream>>>(ei, w, deg, R1, R2, E);
  stats_kernel<<<nb_stats, 256, 0, stream>>>(R2, stats, n);
  finalize_stats<<<1, 64, 0, stream>>>(stats, g1, be1, n);
  bnapply<<<nb_nodes, 256, 0, stream>>>(R2, stats, al1, R1, n);  // h1 -> R1

  // ---- layer 2 ----
  gemm_valu<<<nb_gemm, 256, 0, stream>>>(R1, W2, R2, n);         // xl2 -> R2
  init_acc<<<nb_nodes, 256, 0, stream>>>(R2, deg, b2, R1, n);    // acc2 -> R1
  scatter_kernel<<<nb_edges, 256, 0, stream>>>(ei, w, deg, R2, R1, E);
  hipMemsetAsync(stats, 0, 128 * sizeof(float), stream);
  stats_kernel<<<nb_stats, 256, 0, stream>>>(R1, stats, n);
  finalize_stats<<<1, 64, 0, stream>>>(stats, g2, be2, n);
  bnapply<<<nb_nodes, 256, 0, stream>>>(R1, stats, al2, out, n);
}